// Round 1
// baseline (15329.234 us; speedup 1.0000x reference)
//
#include <hip/hip_runtime.h>
#include <hip/hip_fp16.h>

// Problem: B=32, T=128, Din=H=C=1024, S=128.
// Restructured:
//   Kpre[b,s,h] = sum_c context[b,s,c]*Wq[c,h]          (precomputed)
//   CWT [b,n,s] = sum_c context[b,s,c]*Wout[n,c]        (precomputed, transposed for reads)
//   per step: gates = [x_t;attn;h] @ Wcat^T + bias -> cell -> h
//             scores[b,s] = h[b].Kpre[b,s]; softmax
//             attn[b,n] = tanh( (sum_s a*CWT[b,n,s])/l + sum_h h*Wh[n,h] + b_out[n] )

#define TB 128
#define NB 32

// ws layout (bytes)
#define OFF_XF16  ((size_t)0)          // [32][128][1024] f16   8,388,608
#define OFF_WCAT  ((size_t)8388608)    // [4096][3072]   f16  25,165,824
#define OFF_BCAT  ((size_t)33554432)   // [1024][2048]   f16   4,194,304
#define OFF_KPRE  ((size_t)37748736)   // [32][128][1024]f16   8,388,608
#define OFF_CWT   ((size_t)46137344)   // [32][1024][128]f16   8,388,608
#define OFF_WH    ((size_t)54525952)   // [1024][1024]   f16   2,097,152
#define OFF_BIAS  ((size_t)56623104)   // [4096]         f32      16,384
#define OFF_C     ((size_t)56639488)   // [32][1024]     f32     131,072
#define OFF_H     ((size_t)56770560)   // [2][32][1024]  f16     131,072
#define OFF_ATTN  ((size_t)56901632)   // [32][1024]     f16      65,536
#define OFF_SCORE ((size_t)56967168)   // [32][128]      f32      16,384

__device__ __forceinline__ float dot8(const float4& wv, const float4& iv, float acc) {
  const __half* w = (const __half*)&wv;
  const __half* a = (const __half*)&iv;
#pragma unroll
  for (int j = 0; j < 8; ++j) acc = fmaf(__half2float(w[j]), __half2float(a[j]), acc);
  return acc;
}

// ---------------- one-time conversion kernels ----------------

__global__ __launch_bounds__(256) void k_cvt_x(const float* __restrict__ x, __half* __restrict__ xf) {
  int i = blockIdx.x * 256 + threadIdx.x;           // 1,048,576 float4s
  float4 v = ((const float4*)x)[i];
  __half h4[4] = {__float2half(v.x), __float2half(v.y), __float2half(v.z), __float2half(v.w)};
  ((float2*)xf)[i] = *(float2*)h4;
}

__global__ __launch_bounds__(256) void k_build_wcat(const float* __restrict__ wih,
                                                    const float* __restrict__ whh,
                                                    __half* __restrict__ wcat) {
  int k = blockIdx.x * 256 + threadIdx.x;           // 0..3071
  int r = blockIdx.y;                               // 0..4095
  float v = (k < 2048) ? wih[r * 2048 + k] : whh[r * 1024 + (k - 2048)];
  wcat[r * 3072 + k] = __float2half(v);
}

__global__ __launch_bounds__(256) void k_build_bcat(const float* __restrict__ wq,
                                                    const float* __restrict__ wout,
                                                    __half* __restrict__ bcat) {
  int j = blockIdx.x * 256 + threadIdx.x;           // 0..2047
  int c = blockIdx.y;                               // 0..1023
  float v = (j < 1024) ? wq[c * 1024 + j] : wout[(j - 1024) * 2048 + c];
  bcat[c * 2048 + j] = __float2half(v);
}

__global__ __launch_bounds__(256) void k_cvt_wh(const float* __restrict__ wout, __half* __restrict__ wh) {
  int hh = blockIdx.x * 256 + threadIdx.x;          // 0..1023
  int n = blockIdx.y;
  wh[n * 1024 + hh] = __float2half(wout[n * 2048 + 1024 + hh]);
}

__global__ __launch_bounds__(256) void k_bias(const float* __restrict__ bih,
                                              const float* __restrict__ bhh,
                                              float* __restrict__ bias) {
  int i = blockIdx.x * 256 + threadIdx.x;
  bias[i] = bih[i] + bhh[i];
}

// ---------------- precompute GEMM: [4096 x 1024] fp32 @ [1024 x 2048] f16 ----------------
// n<1024 -> Kpre[m][n] ; n>=1024 -> CWT[b][n-1024][s] with m = b*128+s

__global__ __launch_bounds__(256) void k_pregemm(const float* __restrict__ Af,
                                                 const __half* __restrict__ Bh,
                                                 __half* __restrict__ kpre,
                                                 __half* __restrict__ cwt) {
  __shared__ __half As[32][68];   // [k][m], padded
  __shared__ __half Bs[32][72];   // [k][n], padded
  int tid = threadIdx.x;
  int tx = tid & 15, ty = tid >> 4;
  int m0 = blockIdx.x * 64;       // gridDim.x = 64
  int n0 = blockIdx.y * 64;       // gridDim.y = 32
  float acc[4][4] = {};
  int arow = tid >> 2;            // 0..63
  int akq = (tid & 3) * 8;        // 0,8,16,24
  int brow = tid >> 3;            // 0..31
  int bcol = (tid & 7) * 8;

  for (int k0 = 0; k0 < 1024; k0 += 32) {
    const float* ap = Af + (size_t)(m0 + arow) * 1024 + k0 + akq;
    float4 a0 = *(const float4*)ap;
    float4 a1 = *(const float4*)(ap + 4);
    As[akq + 0][arow] = __float2half(a0.x);
    As[akq + 1][arow] = __float2half(a0.y);
    As[akq + 2][arow] = __float2half(a0.z);
    As[akq + 3][arow] = __float2half(a0.w);
    As[akq + 4][arow] = __float2half(a1.x);
    As[akq + 5][arow] = __float2half(a1.y);
    As[akq + 6][arow] = __float2half(a1.z);
    As[akq + 7][arow] = __float2half(a1.w);
    float4 bv = *(const float4*)(Bh + (size_t)(k0 + brow) * 2048 + n0 + bcol);
    *(float4*)&Bs[brow][bcol] = bv;
    __syncthreads();
#pragma unroll
    for (int k = 0; k < 32; ++k) {
      float2 avv = *(const float2*)&As[k][ty * 4];
      float2 bvv = *(const float2*)&Bs[k][tx * 4];
      const __half* ah = (const __half*)&avv;
      const __half* bh2 = (const __half*)&bvv;
#pragma unroll
      for (int i = 0; i < 4; ++i) {
        float af = __half2float(ah[i]);
#pragma unroll
        for (int j = 0; j < 4; ++j)
          acc[i][j] = fmaf(af, __half2float(bh2[j]), acc[i][j]);
      }
    }
    __syncthreads();
  }

  if (n0 < 1024) {
#pragma unroll
    for (int i = 0; i < 4; ++i) {
      int m = m0 + ty * 4 + i;
      __half o4[4] = {__float2half(acc[i][0]), __float2half(acc[i][1]),
                      __float2half(acc[i][2]), __float2half(acc[i][3])};
      *(float2*)&kpre[(size_t)m * 1024 + n0 + tx * 4] = *(float2*)o4;
    }
  } else {
    int b = m0 >> 7;
    int s0 = (m0 & 127) + ty * 4;
#pragma unroll
    for (int j = 0; j < 4; ++j) {
      int nl = (n0 - 1024) + tx * 4 + j;
      __half o4[4] = {__float2half(acc[0][j]), __float2half(acc[1][j]),
                      __float2half(acc[2][j]), __float2half(acc[3][j])};
      *(float2*)&cwt[((size_t)b * 1024 + nl) * 128 + s0] = *(float2*)o4;
    }
  }
}

// ---------------- per-step kernel 1: gates + cell ----------------
// 256 blocks x 512 threads; block owns 4 h-units (16 gate rows), all 32 batches.

__global__ __launch_bounds__(512) void k_step_gates(const __half* __restrict__ xf,
                                                    const __half* __restrict__ wcat,
                                                    const float* __restrict__ bias,
                                                    const __half* __restrict__ hprev,
                                                    const __half* __restrict__ attn,
                                                    __half* __restrict__ hcur,
                                                    float* __restrict__ cbuf,
                                                    int t) {
  __shared__ __half inp[32][520];   // 512 + 8 pad
  __shared__ float gsh[32][17];
  int tid = threadIdx.x;
  int rl = tid & 15, b = tid >> 4;
  int u0 = blockIdx.x * 4;
  int g = rl >> 2, ul = rl & 3;
  int grow = g * 1024 + u0 + ul;
  const __half* wrow = wcat + (size_t)grow * 3072;
  float acc = 0.f;

  for (int ch = 0; ch < 6; ++ch) {
    const __half* src;
    if (ch < 2)      src = xf + ((size_t)b * TB + t) * 1024 + ch * 512;
    else if (ch < 4) src = attn + (size_t)b * 1024 + (ch - 2) * 512;
    else             src = hprev + (size_t)b * 1024 + (ch - 4) * 512;
#pragma unroll
    for (int i = 0; i < 4; ++i) {
      int col = i * 128 + (tid & 15) * 8;
      *(float4*)&inp[b][col] = *(const float4*)(src + col);
    }
    __syncthreads();
#pragma unroll 8
    for (int k = 0; k < 512; k += 8) {
      float4 wv = *(const float4*)(wrow + ch * 512 + k);
      float4 iv = *(const float4*)&inp[b][k];
      acc = dot8(wv, iv, acc);
    }
    __syncthreads();
  }

  gsh[b][rl] = acc + bias[grow];
  __syncthreads();
  if (tid < 128) {
    int bb = tid >> 2, uu = tid & 3;
    float gi = gsh[bb][uu];
    float gf = gsh[bb][4 + uu];
    float gg = gsh[bb][8 + uu];
    float go = gsh[bb][12 + uu];
    int idx = bb * 1024 + u0 + uu;
    float cold = cbuf[idx];
    float si = 1.f / (1.f + __expf(-gi));
    float sf = 1.f / (1.f + __expf(-gf));
    float so = 1.f / (1.f + __expf(-go));
    float cn = sf * cold + si * tanhf(gg);
    cbuf[idx] = cn;
    hcur[idx] = __float2half(so * tanhf(cn));
  }
}

// ---------------- per-step kernel 2: scores ----------------
// 256 blocks x 256 threads; block = (batch, 16 s-rows)

__global__ __launch_bounds__(256) void k_step_scores(const __half* __restrict__ hcur,
                                                     const __half* __restrict__ kpre,
                                                     float* __restrict__ scores) {
  __shared__ __half hsh[1024];
  __shared__ float red[16][17];
  int tid = threadIdx.x;
  int b = blockIdx.x >> 3;
  int s0 = (blockIdx.x & 7) * 16;
  *(float2*)&hsh[tid * 4] = *(const float2*)(hcur + b * 1024 + tid * 4);
  __syncthreads();
  int sl = tid & 15, kq = tid >> 4;   // kq 0..15 -> 64 k each
  const __half* krow = kpre + ((size_t)(b * 128 + s0 + sl)) * 1024 + kq * 64;
  float p = 0.f;
#pragma unroll
  for (int k = 0; k < 64; k += 8) {
    float4 kv = *(const float4*)(krow + k);
    float4 hv = *(const float4*)&hsh[kq * 64 + k];
    p = dot8(kv, hv, p);
  }
  red[sl][kq] = p;
  __syncthreads();
  if (tid < 16) {
    float s = 0.f;
#pragma unroll
    for (int j = 0; j < 16; ++j) s += red[tid][j];
    scores[b * 128 + s0 + tid] = s;
  }
}

// ---------------- per-step kernel 3: softmax + output projection ----------------
// 256 blocks x 256 threads; block owns 4 output cols for all batches.

__global__ __launch_bounds__(256) void k_step_out(const __half* __restrict__ hcur,
                                                  const __half* __restrict__ cwt,
                                                  const __half* __restrict__ wh,
                                                  const float* __restrict__ scores,
                                                  const float* __restrict__ bout,
                                                  __half* __restrict__ attn,
                                                  float* __restrict__ out,
                                                  int t) {
  __shared__ float al[32][132];
  __shared__ float red[32][9];
  __shared__ float lsum[32];
  __shared__ float part[256];
  int tid = threadIdx.x;
  int n0 = blockIdx.x * 4;

#pragma unroll
  for (int i = 0; i < 4; ++i) {
    int e = i * 1024 + tid * 4;
    float4 v = *(const float4*)&scores[e];
    *(float4*)&al[e >> 7][e & 127] = v;
  }
  __syncthreads();

  int jb = tid >> 3, jj = tid & 7;
  float mx = -1e30f;
#pragma unroll
  for (int s2 = 0; s2 < 16; ++s2) mx = fmaxf(mx, al[jb][jj * 16 + s2]);
  red[jb][jj] = mx;
  __syncthreads();
  if (jj == 0) {
    float m2 = red[jb][0];
#pragma unroll
    for (int j2 = 1; j2 < 8; ++j2) m2 = fmaxf(m2, red[jb][j2]);
    red[jb][8] = m2;
  }
  __syncthreads();
  float m = red[jb][8];
  float es = 0.f;
#pragma unroll
  for (int s2 = 0; s2 < 16; ++s2) {
    float e = __expf(al[jb][jj * 16 + s2] - m);
    al[jb][jj * 16 + s2] = e;
    es += e;
  }
  red[jb][jj] = es;   // [0..7] distinct from [8]; no race with the m read
  __syncthreads();
  if (jj == 0) {
    float l2 = 0.f;
#pragma unroll
    for (int j2 = 0; j2 < 8; ++j2) l2 += red[jb][j2];
    lsum[jb] = l2;
  }
  __syncthreads();

  int nl = jj >> 1, hf = jj & 1;
  int n = n0 + nl;
  const __half* hrow = hcur + jb * 1024 + hf * 512;
  const __half* wrow = wh + (size_t)n * 1024 + hf * 512;
  float pwh = 0.f;
#pragma unroll 4
  for (int k = 0; k < 512; k += 8) {
    float4 wv = *(const float4*)(wrow + k);
    float4 hv = *(const float4*)(hrow + k);
    pwh = dot8(wv, hv, pwh);
  }
  part[tid] = pwh;
  float pctx = 0.f;
  if (hf == 0) {
    const __half* crow = cwt + ((size_t)jb * 1024 + n) * 128;
#pragma unroll 2
    for (int s2 = 0; s2 < 128; s2 += 8) {
      float4 cv = *(const float4*)(crow + s2);
      const __half* ch = (const __half*)&cv;
#pragma unroll
      for (int j2 = 0; j2 < 8; ++j2)
        pctx = fmaf(al[jb][s2 + j2], __half2float(ch[j2]), pctx);
    }
  }
  __syncthreads();
  if (hf == 0) {
    float val = pctx / lsum[jb] + part[tid] + part[tid + 1] + bout[n];
    float a = tanhf(val);
    attn[jb * 1024 + n] = __float2half(a);
    out[((size_t)jb * TB + t) * 1024 + n] = a;
  }
}

// ---------------- launcher ----------------

extern "C" void kernel_launch(void* const* d_in, const int* in_sizes, int n_in,
                              void* d_out, int out_size, void* d_ws, size_t ws_size,
                              hipStream_t stream) {
  const float* x    = (const float*)d_in[0];
  const float* ctxp = (const float*)d_in[1];
  const float* wih  = (const float*)d_in[2];
  const float* whh  = (const float*)d_in[3];
  const float* bih  = (const float*)d_in[4];
  const float* bhh  = (const float*)d_in[5];
  const float* wq   = (const float*)d_in[6];
  const float* wout = (const float*)d_in[7];
  const float* bo   = (const float*)d_in[8];
  float* out = (float*)d_out;
  char* ws = (char*)d_ws;

  __half* xf   = (__half*)(ws + OFF_XF16);
  __half* wcat = (__half*)(ws + OFF_WCAT);
  __half* bcat = (__half*)(ws + OFF_BCAT);
  __half* kpre = (__half*)(ws + OFF_KPRE);
  __half* cwt  = (__half*)(ws + OFF_CWT);
  __half* whf  = (__half*)(ws + OFF_WH);
  float*  bias = (float*)(ws + OFF_BIAS);
  float*  cbuf = (float*)(ws + OFF_C);
  __half* hbuf = (__half*)(ws + OFF_H);
  __half* attn = (__half*)(ws + OFF_ATTN);
  float*  sc   = (float*)(ws + OFF_SCORE);

  // zero c, h[0], h[1], attn (contiguous region)
  hipMemsetAsync(ws + OFF_C, 0, 327680, stream);

  hipLaunchKernelGGL(k_cvt_x, dim3(4096), dim3(256), 0, stream, x, xf);
  hipLaunchKernelGGL(k_build_wcat, dim3(12, 4096), dim3(256), 0, stream, wih, whh, wcat);
  hipLaunchKernelGGL(k_build_bcat, dim3(8, 1024), dim3(256), 0, stream, wq, wout, bcat);
  hipLaunchKernelGGL(k_cvt_wh, dim3(4, 1024), dim3(256), 0, stream, wout, whf);
  hipLaunchKernelGGL(k_bias, dim3(16), dim3(256), 0, stream, bih, bhh, bias);
  hipLaunchKernelGGL(k_pregemm, dim3(64, 32), dim3(256), 0, stream, ctxp, bcat, kpre, cwt);

  for (int t = 0; t < TB; ++t) {
    int cur = t & 1;
    __half* hc = hbuf + cur * 32768;
    __half* hp = hbuf + (cur ^ 1) * 32768;
    hipLaunchKernelGGL(k_step_gates, dim3(256), dim3(512), 0, stream, xf, wcat, bias, hp, attn, hc, cbuf, t);
    hipLaunchKernelGGL(k_step_scores, dim3(256), dim3(256), 0, stream, hc, kpre, sc);
    hipLaunchKernelGGL(k_step_out, dim3(256), dim3(256), 0, stream, hc, cwt, whf, sc, bo, attn, out, t);
  }
}

// Round 2
// 4150.306 us; speedup vs baseline: 3.6935x; 3.6935x over previous
//
#include <hip/hip_runtime.h>
#include <hip/hip_fp16.h>

// B=32, T=128, Din=H=C=1024, S=128.
// Restructure (R2): MFMA 16x16x32_f16 for gates & out-proj with PRE-PACKED
// weight fragment streams (coalesced 1KB/wave loads); LDS-staged activations
// with pad (row stride = +4 banks -> uniform bank spread); transposed
// KpreT/CWT layouts so per-step attention reads are coalesced.
//
// MFMA layout (guide §3, m89-verified, dtype-independent):
//   A[16x32]: lane l, elem j -> A[l&15][(l>>4)*8+j]
//   B[32x16]: lane l, elem j -> B[(l>>4)*8+j][l&15]
//   D[16x16]: lane l, reg  r -> D[(l>>4)*4+r][l&15]
// Gate rows packed as r' = u*4+gate  =>  lane reg r == gate r of unit
// u = mt*4 + (l>>4): cell update is fully lane-local.

typedef _Float16 f16x8 __attribute__((ext_vector_type(8)));
typedef float f32x4 __attribute__((ext_vector_type(4)));

// ---- workspace layout (bytes) ----
#define OFF_XF16  ((size_t)0)           // [32][128][1024] f16     8,388,608
#define OFF_WP    ((size_t)8388608)     // [256][96][64][8] f16   25,165,824
#define OFF_WHP   ((size_t)33554432)    // [64][32][64][8] f16     2,097,152
#define OFF_BCAT  ((size_t)35651584)    // [1024][2048] f16        4,194,304
#define OFF_KPT   ((size_t)39845888)    // [32][1024][128] f16     8,388,608
#define OFF_CWT   ((size_t)48234496)    // [32][1024][128] f16     8,388,608
#define OFF_BIASR ((size_t)56623104)    // [4096] f32                 16,384
#define OFF_CBUF  ((size_t)56639488)    // [1024][32] f32 (u-major)  131,072
#define OFF_H2    ((size_t)56770560)    // [2][32][1024] f16         131,072
#define OFF_ATTN  ((size_t)56901632)    // [32][1024] f16             65,536
#define OFF_ANORM ((size_t)56967168)    // [32][128] f32              16,384

// ---------------- one-time kernels ----------------

__global__ __launch_bounds__(256) void k_cvt_x(const float* __restrict__ x, __half* __restrict__ xf) {
  int i = blockIdx.x * 256 + threadIdx.x;           // 1,048,576 float4s
  float4 v = ((const float4*)x)[i];
  __half h4[4] = {__float2half(v.x), __float2half(v.y), __float2half(v.z), __float2half(v.w)};
  ((float2*)xf)[i] = *(float2*)h4;
}

__global__ __launch_bounds__(256) void k_build_bcat(const float* __restrict__ wq,
                                                    const float* __restrict__ wout,
                                                    __half* __restrict__ bcat) {
  int j = blockIdx.x * 256 + threadIdx.x;           // 0..2047
  int c = blockIdx.y;                               // 0..1023
  float v = (j < 1024) ? wq[c * 1024 + j] : wout[(size_t)(j - 1024) * 2048 + c];
  bcat[c * 2048 + j] = __float2half(v);
}

// pack gate weights into MFMA A-fragment stream order.
// wp[((mt*96+ks)*64+l)*8+j] = W'[mt*16+(l&15)][ks*32+(l>>4)*8+j]
// row reorder: r' = u*4+gate ; original row = gate*1024+u
// k<2048 -> W_ih[row][k] ([x;attn]), k>=2048 -> W_hh[row][k-2048]
__global__ __launch_bounds__(256) void k_pack_wp(const float* __restrict__ wih,
                                                 const float* __restrict__ whh,
                                                 __half* __restrict__ wpo) {
  int mt = blockIdx.x;                 // 0..255
  int tid = threadIdx.x;
  int ks = blockIdx.y * 4 + (tid >> 6);  // 0..95
  int l = tid & 63;
  int rp = mt * 16 + (l & 15);
  int u = rp >> 2, g = rp & 3;
  int row = g * 1024 + u;
  int k = ks * 32 + (l >> 4) * 8;
  const float* src = (k < 2048) ? (wih + (size_t)row * 2048 + k)
                                : (whh + (size_t)row * 1024 + (k - 2048));
  float4 a = *(const float4*)src;
  float4 b = *(const float4*)(src + 4);
  __half o[8] = {__float2half(a.x), __float2half(a.y), __float2half(a.z), __float2half(a.w),
                 __float2half(b.x), __float2half(b.y), __float2half(b.z), __float2half(b.w)};
  *(float4*)(wpo + (((size_t)mt * 96 + ks) * 64 + l) * 8) = *(float4*)o;
}

// pack out-proj h-part weights: rows = n (no reorder), k over h (Wout[:,1024:])
__global__ __launch_bounds__(256) void k_pack_whp(const float* __restrict__ wout,
                                                  __half* __restrict__ wpo) {
  int nt = blockIdx.x;                 // 0..63
  int tid = threadIdx.x;
  int ks = blockIdx.y * 4 + (tid >> 6);  // 0..31
  int l = tid & 63;
  int row = nt * 16 + (l & 15);
  int k = ks * 32 + (l >> 4) * 8;
  const float* src = wout + (size_t)row * 2048 + 1024 + k;
  float4 a = *(const float4*)src;
  float4 b = *(const float4*)(src + 4);
  __half o[8] = {__float2half(a.x), __float2half(a.y), __float2half(a.z), __float2half(a.w),
                 __float2half(b.x), __float2half(b.y), __float2half(b.z), __float2half(b.w)};
  *(float4*)(wpo + (((size_t)nt * 32 + ks) * 64 + l) * 8) = *(float4*)o;
}

__global__ __launch_bounds__(256) void k_bias_r(const float* __restrict__ bih,
                                                const float* __restrict__ bhh,
                                                float* __restrict__ biasr) {
  int i = blockIdx.x * 256 + threadIdx.x;   // 0..4095, r' = u*4+g
  int u = i >> 2, g = i & 3;
  biasr[i] = bih[g * 1024 + u] + bhh[g * 1024 + u];
}

// precompute GEMM: [4096 x 1024] fp32 @ [1024 x 2048] f16.
// n<1024 -> KpreT[b][n][s] ; n>=1024 -> CWT[b][n-1024][s]  (both transposed)
__global__ __launch_bounds__(256) void k_pregemm(const float* __restrict__ Af,
                                                 const __half* __restrict__ Bh,
                                                 __half* __restrict__ kpT,
                                                 __half* __restrict__ cwt) {
  __shared__ __half As[32][68];
  __shared__ __half Bs[32][72];
  int tid = threadIdx.x;
  int tx = tid & 15, ty = tid >> 4;
  int m0 = blockIdx.x * 64;
  int n0 = blockIdx.y * 64;
  float acc[4][4] = {};
  int arow = tid >> 2;
  int akq = (tid & 3) * 8;
  int brow = tid >> 3;
  int bcol = (tid & 7) * 8;

  for (int k0 = 0; k0 < 1024; k0 += 32) {
    const float* ap = Af + (size_t)(m0 + arow) * 1024 + k0 + akq;
    float4 a0 = *(const float4*)ap;
    float4 a1 = *(const float4*)(ap + 4);
    As[akq + 0][arow] = __float2half(a0.x);
    As[akq + 1][arow] = __float2half(a0.y);
    As[akq + 2][arow] = __float2half(a0.z);
    As[akq + 3][arow] = __float2half(a0.w);
    As[akq + 4][arow] = __float2half(a1.x);
    As[akq + 5][arow] = __float2half(a1.y);
    As[akq + 6][arow] = __float2half(a1.z);
    As[akq + 7][arow] = __float2half(a1.w);
    float4 bv = *(const float4*)(Bh + (size_t)(k0 + brow) * 2048 + n0 + bcol);
    *(float4*)&Bs[brow][bcol] = bv;
    __syncthreads();
#pragma unroll
    for (int k = 0; k < 32; ++k) {
      float2 avv = *(const float2*)&As[k][ty * 4];
      float2 bvv = *(const float2*)&Bs[k][tx * 4];
      const __half* ah = (const __half*)&avv;
      const __half* bh2 = (const __half*)&bvv;
#pragma unroll
      for (int i = 0; i < 4; ++i) {
        float af = __half2float(ah[i]);
#pragma unroll
        for (int j = 0; j < 4; ++j)
          acc[i][j] = fmaf(af, __half2float(bh2[j]), acc[i][j]);
      }
    }
    __syncthreads();
  }

  int b = m0 >> 7;
  int s0 = (m0 & 127) + ty * 4;
  __half* dst;
  int nl;
  if (n0 < 1024) { dst = kpT; nl = n0 + tx * 4; }
  else           { dst = cwt; nl = n0 - 1024 + tx * 4; }
#pragma unroll
  for (int j = 0; j < 4; ++j) {
    __half o4[4] = {__float2half(acc[0][j]), __float2half(acc[1][j]),
                    __float2half(acc[2][j]), __float2half(acc[3][j])};
    *(float2*)&dst[((size_t)b * 1024 + nl + j) * 128 + s0] = *(float2*)o4;
  }
}

// ---------------- per-step kernel 1: gates MFMA + cell ----------------
// grid 256 (one m-tile of 16 packed gate rows = 4 units x 4 gates), 512 thr.
// wave w: bh = w&1 (batch half), kq = w>>1 (k quarter of chunk).
// inp LDS [32][1544] f16 (pad: row stride 3088B -> Dbank 4).

__global__ __launch_bounds__(512) void k_gates(const __half* __restrict__ xf,
                                               const f16x8* __restrict__ wp,
                                               const float* __restrict__ biasr,
                                               const __half* __restrict__ hprev,
                                               const __half* __restrict__ attn,
                                               __half* __restrict__ hcur,
                                               float* __restrict__ cbuf,
                                               int t) {
  __shared__ __half inp[32 * 1544];      // 98,816 B
  __shared__ float red[6 * 64 * 4];      // 6 KB
  int tid = threadIdx.x;
  int mt = blockIdx.x;
  int w = tid >> 6, l = tid & 63;
  int bh = w & 1, kq = w >> 1;
  int rl = l & 15, kg = l >> 4;
  f32x4 acc = {0.f, 0.f, 0.f, 0.f};

  for (int c = 0; c < 2; ++c) {
    // stage chunk c: 32 rows x 1536 halves = 6144 16B units, 12/thread
#pragma unroll
    for (int i = 0; i < 12; ++i) {
      int f = i * 512 + tid;
      int b = f / 192;
      int u = f - b * 192;
      int k0 = c * 1536 + u * 8;
      const __half* src;
      if (k0 < 1024)      src = xf + (((size_t)b * 128 + t) << 10) + k0;
      else if (k0 < 2048) src = attn + ((size_t)b << 10) + (k0 - 1024);
      else                src = hprev + ((size_t)b << 10) + (k0 - 2048);
      float4 v = *(const float4*)src;
      *(float4*)((char*)inp + b * 3088 + u * 16) = v;
    }
    __syncthreads();
    const char* brow = (const char*)inp + (bh * 16 + rl) * 3088 + kg * 16;
    const f16x8* wpp = wp + (((size_t)mt * 96 + c * 48 + kq * 12) * 64 + l);
#pragma unroll 4
    for (int q = 0; q < 12; ++q) {
      f16x8 af = wpp[q * 64];
      f16x8 bf = *(const f16x8*)(brow + (kq * 12 + q) * 64);
      acc = __builtin_amdgcn_mfma_f32_16x16x32_f16(af, bf, acc, 0, 0, 0);
    }
    __syncthreads();
  }

  if (w >= 2) *(f32x4*)&red[((w - 2) * 64 + l) * 4] = acc;
  __syncthreads();
  if (w < 2) {
#pragma unroll
    for (int p = 0; p < 3; ++p) {
      f32x4 o = *(f32x4*)&red[((2 * p + w) * 64 + l) * 4];
      acc[0] += o[0]; acc[1] += o[1]; acc[2] += o[2]; acc[3] += o[3];
    }
    float4 bv = *(const float4*)&biasr[mt * 16 + kg * 4];
    float gi = acc[0] + bv.x;
    float gf = acc[1] + bv.y;
    float gg = acc[2] + bv.z;
    float go = acc[3] + bv.w;
    int u = mt * 4 + kg;
    int b = bh * 16 + rl;
    int ci = u * 32 + b;
    float cold = cbuf[ci];
    float si = 1.f / (1.f + __expf(-gi));
    float sf = 1.f / (1.f + __expf(-gf));
    float so = 1.f / (1.f + __expf(-go));
    float cn = sf * cold + si * tanhf(gg);
    cbuf[ci] = cn;
    hcur[((size_t)b << 10) + u] = __float2half(so * tanhf(cn));
  }
}

// ---------------- per-step kernel 2: scores + softmax ----------------
// grid 32 (1/batch) x 512. KpreT[b][k][s] -> coalesced 256B/instr loads.

__global__ __launch_bounds__(512) void k_scores(const __half* __restrict__ hcur,
                                                const __half* __restrict__ kpT,
                                                float* __restrict__ anorm) {
  __shared__ __half hs[1024];
  __shared__ float part[16][132];
  __shared__ float sc[128];
  __shared__ float bcast[2];
  int b = blockIdx.x, tid = threadIdx.x;
  if (tid < 256) *(float2*)&hs[tid * 4] = *(const float2*)(hcur + ((size_t)b << 10) + tid * 4);
  __syncthreads();
  int sg = tid & 31, ke = tid >> 5;          // ke 0..15, 64 k each
  float a0 = 0, a1 = 0, a2 = 0, a3 = 0;
  const __half* base = kpT + ((size_t)b << 17) + sg * 4;
  for (int k = ke * 64; k < ke * 64 + 64; ++k) {
    float hv = __half2float(hs[k]);
    float2 kv = *(const float2*)(base + (size_t)k * 128);
    const __half* kh = (const __half*)&kv;
    a0 = fmaf(hv, __half2float(kh[0]), a0);
    a1 = fmaf(hv, __half2float(kh[1]), a1);
    a2 = fmaf(hv, __half2float(kh[2]), a2);
    a3 = fmaf(hv, __half2float(kh[3]), a3);
  }
  float4 pv = {a0, a1, a2, a3};
  *(float4*)&part[ke][sg * 4] = pv;
  __syncthreads();
  if (tid < 128) {
    float s = 0.f;
#pragma unroll
    for (int e = 0; e < 16; ++e) s += part[e][tid];
    sc[tid] = s;
  }
  __syncthreads();
  if (tid < 64) {
    float v = fmaxf(sc[tid], sc[tid + 64]);
#pragma unroll
    for (int off = 32; off; off >>= 1) v = fmaxf(v, __shfl_xor(v, off));
    if (tid == 0) bcast[0] = v;
  }
  __syncthreads();
  float mx = bcast[0];
  if (tid < 128) sc[tid] = __expf(sc[tid] - mx);
  __syncthreads();
  if (tid < 64) {
    float v = sc[tid] + sc[tid + 64];
#pragma unroll
    for (int off = 32; off; off >>= 1) v += __shfl_xor(v, off);
    if (tid == 0) bcast[1] = 1.f / v;
  }
  __syncthreads();
  if (tid < 128) anorm[(b << 7) + tid] = sc[tid] * bcast[1];
}

// ---------------- per-step kernel 3: out-proj MFMA + ctx + tanh ----------------
// grid 128 (nt 0..63 x bh 0..1) x 256. wave w = k-quarter; ctx split by s.

__global__ __launch_bounds__(256) void k_out(const __half* __restrict__ hcur,
                                             const f16x8* __restrict__ whp,
                                             const __half* __restrict__ cwt,
                                             const float* __restrict__ anorm,
                                             const float* __restrict__ bout,
                                             __half* __restrict__ attn,
                                             float* __restrict__ out,
                                             int t) {
  __shared__ __half hsl[16 * 1032];      // 33,024 B (pad: 2064B row -> Dbank 4)
  __shared__ float al[16][132];          // 8448 B
  __shared__ float red[3 * 64 * 4];
  __shared__ float red2[3 * 64 * 4];
  int tid = threadIdx.x;
  int nt = blockIdx.x >> 1, bh = blockIdx.x & 1;
  int w = tid >> 6, l = tid & 63;
  int rl = l & 15, kg = l >> 4;

#pragma unroll
  for (int i = 0; i < 8; ++i) {
    int f = i * 256 + tid;               // 2048 16B units
    int b = f >> 7, u = f & 127;
    float4 v = *(const float4*)(hcur + (((size_t)bh * 16 + b) << 10) + u * 8);
    *(float4*)((char*)hsl + b * 2064 + u * 16) = v;
  }
#pragma unroll
  for (int i = 0; i < 2; ++i) {
    int f = i * 256 + tid;               // 512 float4 units
    int b = f >> 5, c4 = (f & 31) * 4;
    float4 v = *(const float4*)(anorm + (((size_t)bh * 16 + b) << 7) + c4);
    *(float4*)&al[b][c4] = v;
  }
  __syncthreads();

  f32x4 acc = {0.f, 0.f, 0.f, 0.f};
  const char* brow = (const char*)hsl + rl * 2064 + kg * 16;
  const f16x8* wpp = whp + (((size_t)nt * 32 + w * 8) * 64 + l);
#pragma unroll 4
  for (int q = 0; q < 8; ++q) {
    f16x8 af = wpp[q * 64];
    f16x8 bf = *(const f16x8*)(brow + (w * 8 + q) * 64);
    acc = __builtin_amdgcn_mfma_f32_16x16x32_f16(af, bf, acc, 0, 0, 0);
  }

  // ctx partials: wave w covers s in [w*32, w*32+32)
  float pc0 = 0, pc1 = 0, pc2 = 0, pc3 = 0;
  int b = bh * 16 + rl;
  int n0 = nt * 16 + kg * 4;
  const __half* cw = cwt + (((size_t)b << 10) + n0) * 128;
  for (int s = w * 32; s < w * 32 + 32; s += 8) {
    float4 c0 = *(const float4*)(cw + 0 * 128 + s);
    float4 c1 = *(const float4*)(cw + 1 * 128 + s);
    float4 c2 = *(const float4*)(cw + 2 * 128 + s);
    float4 c3 = *(const float4*)(cw + 3 * 128 + s);
    float4 av0 = *(const float4*)&al[rl][s];
    float4 av1 = *(const float4*)&al[rl][s + 4];
    float aa[8] = {av0.x, av0.y, av0.z, av0.w, av1.x, av1.y, av1.z, av1.w};
    const __half* h0 = (const __half*)&c0;
    const __half* h1 = (const __half*)&c1;
    const __half* h2 = (const __half*)&c2;
    const __half* h3 = (const __half*)&c3;
#pragma unroll
    for (int j = 0; j < 8; ++j) {
      pc0 = fmaf(aa[j], __half2float(h0[j]), pc0);
      pc1 = fmaf(aa[j], __half2float(h1[j]), pc1);
      pc2 = fmaf(aa[j], __half2float(h2[j]), pc2);
      pc3 = fmaf(aa[j], __half2float(h3[j]), pc3);
    }
  }

  if (w >= 1) {
    *(f32x4*)&red[((w - 1) * 64 + l) * 4] = acc;
    float4 pv = {pc0, pc1, pc2, pc3};
    *(float4*)&red2[((w - 1) * 64 + l) * 4] = pv;
  }
  __syncthreads();
  if (w == 0) {
#pragma unroll
    for (int p = 0; p < 3; ++p) {
      f32x4 o = *(f32x4*)&red[(p * 64 + l) * 4];
      float4 o2 = *(float4*)&red2[(p * 64 + l) * 4];
      acc[0] += o[0]; acc[1] += o[1]; acc[2] += o[2]; acc[3] += o[3];
      pc0 += o2.x; pc1 += o2.y; pc2 += o2.z; pc3 += o2.w;
    }
    float4 bv = *(const float4*)&bout[n0];
    float o0 = tanhf(acc[0] + pc0 + bv.x);
    float o1 = tanhf(acc[1] + pc1 + bv.y);
    float o2 = tanhf(acc[2] + pc2 + bv.z);
    float o3 = tanhf(acc[3] + pc3 + bv.w);
    __half o4[4] = {__float2half(o0), __float2half(o1), __float2half(o2), __float2half(o3)};
    *(float2*)&attn[((size_t)b << 10) + n0] = *(float2*)o4;
    float4 ov = {o0, o1, o2, o3};
    *(float4*)&out[(((size_t)b * 128 + t) << 10) + n0] = ov;
  }
}

// ---------------- launcher ----------------

extern "C" void kernel_launch(void* const* d_in, const int* in_sizes, int n_in,
                              void* d_out, int out_size, void* d_ws, size_t ws_size,
                              hipStream_t stream) {
  const float* x    = (const float*)d_in[0];
  const float* ctxp = (const float*)d_in[1];
  const float* wih  = (const float*)d_in[2];
  const float* whh  = (const float*)d_in[3];
  const float* bih  = (const float*)d_in[4];
  const float* bhh  = (const float*)d_in[5];
  const float* wq   = (const float*)d_in[6];
  const float* wout = (const float*)d_in[7];
  const float* bo   = (const float*)d_in[8];
  float* out = (float*)d_out;
  char* ws = (char*)d_ws;

  __half* xf    = (__half*)(ws + OFF_XF16);
  __half* wp    = (__half*)(ws + OFF_WP);
  __half* whp   = (__half*)(ws + OFF_WHP);
  __half* bcat  = (__half*)(ws + OFF_BCAT);
  __half* kpT   = (__half*)(ws + OFF_KPT);
  __half* cwt   = (__half*)(ws + OFF_CWT);
  float*  biasr = (float*)(ws + OFF_BIASR);
  float*  cbuf  = (float*)(ws + OFF_CBUF);
  __half* hbuf  = (__half*)(ws + OFF_H2);
  __half* attn  = (__half*)(ws + OFF_ATTN);
  float*  an    = (float*)(ws + OFF_ANORM);

  // zero c, h[0], h[1], attn (contiguous)
  hipMemsetAsync(ws + OFF_CBUF, 0, 327680, stream);

  hipLaunchKernelGGL(k_cvt_x, dim3(4096), dim3(256), 0, stream, x, xf);
  hipLaunchKernelGGL(k_build_bcat, dim3(8, 1024), dim3(256), 0, stream, wq, wout, bcat);
  hipLaunchKernelGGL(k_pack_wp, dim3(256, 24), dim3(256), 0, stream, wih, whh, wp);
  hipLaunchKernelGGL(k_pack_whp, dim3(64, 8), dim3(256), 0, stream, wout, whp);
  hipLaunchKernelGGL(k_bias_r, dim3(16), dim3(256), 0, stream, bih, bhh, biasr);
  hipLaunchKernelGGL(k_pregemm, dim3(64, 32), dim3(256), 0, stream, ctxp, bcat, kpT, cwt);

  for (int t = 0; t < 128; ++t) {
    __half* hc = hbuf + (t & 1) * 32768;
    __half* hp = hbuf + ((t & 1) ^ 1) * 32768;
    hipLaunchKernelGGL(k_gates, dim3(256), dim3(512), 0, stream,
                       xf, (const f16x8*)wp, biasr, hp, attn, hc, cbuf, t);
    hipLaunchKernelGGL(k_scores, dim3(32), dim3(512), 0, stream, hc, kpT, an);
    hipLaunchKernelGGL(k_out, dim3(128), dim3(256), 0, stream,
                       hc, (const f16x8*)whp, cwt, an, bo, attn, out, t);
  }
}